// Round 1
// baseline (147.539 us; speedup 1.0000x reference)
//
#include <hip/hip_runtime.h>

// SigMMDLoss: paths (B=4096, T=4096) fp32 for real and gen.
// Per-row reductions over increments d_k = p[k+1]-p[k], k in [0, T-2]:
//   A  = sum d_k                    (level1, space channel)
//   S3 = sum t[k+1]*d_k             (level2, (time,space))
//   S4 = sum (p[k+1]-p[0])*d_k      (level2, (space,space))
//   S6 = sum d_k^2                  (level3, space)
//   S8 = sum d_k^3                  (level4, space)
// Time-only features are identical between real/gen -> cancel exactly.
// out = sum_q ( mean_b real_q - mean_b gen_q )^2   (scalar fp32)

constexpr int T_LEN = 4096;
constexpr int B_ROWS = 4096;
constexpr int NINC = T_LEN - 1;   // 4095 increments
constexpr int NQ = 5;
constexpr int PSTRIDE = 2 * B_ROWS; // partials per feature: [which][row]

__device__ inline double wave_red(double x) {
#pragma unroll
  for (int off = 32; off; off >>= 1) x += __shfl_down(x, off, 64);
  return x;
}

__global__ __launch_bounds__(256) void row_sigs(const float* __restrict__ real,
                                                const float* __restrict__ gen,
                                                double* __restrict__ P) {
  const int row = blockIdx.x;
  const int which = blockIdx.y;
  const float* p = (which ? gen : real) + (size_t)row * T_LEN;
  const int tid = threadIdx.x;
  const int base = tid * 16;

  // Load 16 owned elements (4x float4) + 1 overlap element.
  float v[17];
  const float4* p4 = reinterpret_cast<const float4*>(p + base);
#pragma unroll
  for (int j = 0; j < 4; ++j) {
    float4 a = p4[j];
    v[4 * j + 0] = a.x;
    v[4 * j + 1] = a.y;
    v[4 * j + 2] = a.z;
    v[4 * j + 3] = a.w;
  }
  v[16] = (base + 16 < T_LEN) ? p[base + 16] : 0.0f;
  const float p0 = p[0];  // wave-uniform broadcast load

  const float inv = 1.0f / (float)NINC;
  float A = 0.f, s3 = 0.f, s4 = 0.f, s6 = 0.f, s8 = 0.f;
#pragma unroll
  for (int j = 0; j < 16; ++j) {
    const int k = base + j;
    const bool valid = (k < NINC);
    const float d = valid ? (v[j + 1] - v[j]) : 0.0f;
    const float w = (float)(k + 1) * inv;     // ~= t[k+1]
    const float cx = v[j + 1] - p0;           // ~= cumsum of increments
    A += d;
    s3 += w * d;
    s4 += cx * d;
    const float d2 = d * d;
    s6 += d2;
    s8 += d2 * d;
  }

  // Promote to double and block-reduce.
  double r[NQ] = {(double)A, (double)s3, (double)s4, (double)s6, (double)s8};
#pragma unroll
  for (int q = 0; q < NQ; ++q) r[q] = wave_red(r[q]);

  __shared__ double sred[4][NQ];
  const int lane = tid & 63;
  const int wid = tid >> 6;
  if (lane == 0) {
#pragma unroll
    for (int q = 0; q < NQ; ++q) sred[wid][q] = r[q];
  }
  __syncthreads();
  if (tid < NQ) {
    const double s = sred[0][tid] + sred[1][tid] + sred[2][tid] + sred[3][tid];
    // SoA layout: P[q][which*B + row] -> coalesced reads in finalize.
    P[tid * PSTRIDE + which * B_ROWS + row] = s;
  }
}

__global__ __launch_bounds__(256) void finalize_k(const double* __restrict__ P,
                                                  float* __restrict__ out) {
  const int tid = threadIdx.x;
  double loc[NQ] = {0, 0, 0, 0, 0};
  for (int r = tid; r < B_ROWS; r += 256) {
#pragma unroll
    for (int q = 0; q < NQ; ++q)
      loc[q] += P[q * PSTRIDE + r] - P[q * PSTRIDE + B_ROWS + r];
  }
#pragma unroll
  for (int q = 0; q < NQ; ++q) loc[q] = wave_red(loc[q]);

  __shared__ double sred[4][NQ];
  const int lane = tid & 63;
  const int wid = tid >> 6;
  if (lane == 0) {
#pragma unroll
    for (int q = 0; q < NQ; ++q) sred[wid][q] = loc[q];
  }
  __syncthreads();
  if (tid == 0) {
    double o = 0.0;
#pragma unroll
    for (int q = 0; q < NQ; ++q) {
      const double s = sred[0][q] + sred[1][q] + sred[2][q] + sred[3][q];
      const double m = s / (double)B_ROWS;  // mean(real) - mean(gen)
      o += m * m;
    }
    out[0] = (float)o;
  }
}

extern "C" void kernel_launch(void* const* d_in, const int* in_sizes, int n_in,
                              void* d_out, int out_size, void* d_ws, size_t ws_size,
                              hipStream_t stream) {
  const float* real = (const float*)d_in[0];
  const float* gen = (const float*)d_in[1];
  double* P = (double*)d_ws;  // needs NQ * 2 * B_ROWS * 8 = 320 KB
  float* out = (float*)d_out;

  dim3 grid(B_ROWS, 2);
  row_sigs<<<grid, 256, 0, stream>>>(real, gen, P);
  finalize_k<<<1, 256, 0, stream>>>(P, out);
}

// Round 2
// 147.384 us; speedup vs baseline: 1.0010x; 1.0010x over previous
//
#include <hip/hip_runtime.h>

// SigMMDLoss, algebraically flattened.
// Per-row features over increments d_k = p[k+1]-p[k], k in [0, 4094]:
//   A  = sum d            = p[4095] - p[0]                (telescoping, exact)
//   S3 = sum (k+1)/n d    = p[4095] - (1/n) sum_{j<4095} p[j]   (Abel, exact)
//   S4 = sum (p[k+1]-p0)d = (A^2 + S6)/2                  (exact identity)
//   S6 = sum d^2,  S8 = sum d^3
// Time-only features cancel exactly between real and gen.
// => only GLOBAL sums needed: SP = sum p (excl last col), D2 = sum d^2,
//    D3 = sum d^3, plus per-row scalars from p[0], p[4095] only:
//    G1 = sum_rows A, G2 = sum_rows A^2, G3 = sum_rows p[4095].
// out = sum_q ((F_q^real - F_q^gen)/B)^2.

constexpr int T_LEN = 4096;
constexpr int B_ROWS = 4096;
constexpr int NQ = 6;                         // sp, d2, d3, g1, g2, g3
constexpr int SEG = 2048;                     // columns per wave
constexpr int J_IT = SEG / 256;               // 8 float4 iters per lane
constexpr int BLK_PER_WHICH = 2048;           // 4096 rows * 2 segs / 4 waves
constexpr int PSTR = 2 * BLK_PER_WHICH;       // 4096

__global__ __launch_bounds__(256) void sig_flat(const float* __restrict__ real,
                                                const float* __restrict__ gen,
                                                double* __restrict__ P) {
  const int tid = threadIdx.x;
  const int lane = tid & 63;
  const int wid = tid >> 6;
  const int which = blockIdx.y;
  const int gw = blockIdx.x * 4 + wid;        // global wave id within `which`
  const int row = gw >> 1;
  const int seg = gw & 1;
  const float* p_row = (which ? gen : real) + (size_t)row * T_LEN;
  const float* ps = p_row + seg * SEG;
  const float4* q4 = reinterpret_cast<const float4*>(ps);

  // Wave-uniform broadcast extras (1 transaction each, mostly L2-hit):
  const float nxt = p_row[seg == 0 ? SEG : 0];   // p[2048]; only used by seg 0
  const float pnv = p_row[T_LEN - 1];            // p[4095]; only used by seg 0

  float sp = 0.f, s2 = 0.f, s3 = 0.f;
  float first = 0.f, carry = 0.f;
#pragma unroll
  for (int j = 0; j < J_IT; ++j) {
    // col = seg*2048 + j*256 + lane*4  -> wave reads contiguous 1 KB/instr
    float4 a = q4[j * 64 + lane];
    if (j == 0) {
      carry = __shfl(a.x, 0, 64);   // makes lane0-j0 boundary diff = 0
      first = carry;                // p[seg*2048] (p[0] for seg 0)
    }
    float pw = __shfl_up(a.w, 1, 64);          // left neighbor's last element
    float px = (lane == 0) ? carry : pw;
    float d0 = a.x - px;
    float d1 = a.y - a.x;
    float d2 = a.z - a.y;
    float d3 = a.w - a.z;
    float e0 = d0 * d0, e1 = d1 * d1, e2 = d2 * d2, e3 = d3 * d3;
    s2 += (e0 + e1) + (e2 + e3);
    s3 += (e0 * d0 + e1 * d1) + (e2 * d2 + e3 * d3);
    sp += (a.x + a.y) + (a.z + a.w);
    carry = __shfl(a.w, 63, 64);               // wave's last element so far
  }

  double g1 = 0., g2 = 0., g3 = 0.;
  if (lane == 0) {
    if (seg == 0) {
      // segment-boundary increment k = 2047: p[2048] - p[2047]
      float db = nxt - carry;
      s2 += db * db;
      s3 += db * db * db;
      // per-row scalars (exact telescoped features)
      double A = (double)pnv - (double)first;
      g1 = A;
      g2 = A * A;
      g3 = (double)pnv;
    } else {
      sp -= carry;                 // exclude col 4095 from SP
    }
  }

  // fp32 wave reduce (valid on lane 0)
#pragma unroll
  for (int off = 32; off; off >>= 1) {
    sp += __shfl_down(sp, off, 64);
    s2 += __shfl_down(s2, off, 64);
    s3 += __shfl_down(s3, off, 64);
  }

  __shared__ double sred[4][NQ];
  if (lane == 0) {
    sred[wid][0] = (double)sp;
    sred[wid][1] = (double)s2;
    sred[wid][2] = (double)s3;
    sred[wid][3] = g1;
    sred[wid][4] = g2;
    sred[wid][5] = g3;
  }
  __syncthreads();
  if (tid < NQ) {
    double s = sred[0][tid] + sred[1][tid] + sred[2][tid] + sred[3][tid];
    P[tid * PSTR + which * BLK_PER_WHICH + blockIdx.x] = s;
  }
}

__global__ __launch_bounds__(256) void sig_final(const double* __restrict__ P,
                                                 float* __restrict__ out) {
  const int tid = threadIdx.x;
  double loc[NQ] = {0, 0, 0, 0, 0, 0};
  for (int i = tid; i < BLK_PER_WHICH; i += 256) {
#pragma unroll
    for (int q = 0; q < NQ; ++q)
      loc[q] += P[q * PSTR + i] - P[q * PSTR + BLK_PER_WHICH + i];
  }
#pragma unroll
  for (int q = 0; q < NQ; ++q)
#pragma unroll
    for (int off = 32; off; off >>= 1) loc[q] += __shfl_down(loc[q], off, 64);

  __shared__ double sred[4][NQ];
  const int lane = tid & 63, wid = tid >> 6;
  if (lane == 0)
    for (int q = 0; q < NQ; ++q) sred[wid][q] = loc[q];
  __syncthreads();
  if (tid == 0) {
    double Q[NQ];
    for (int q = 0; q < NQ; ++q)
      Q[q] = sred[0][q] + sred[1][q] + sred[2][q] + sred[3][q];
    const double n = (double)(T_LEN - 1), Bn = (double)B_ROWS;
    const double dSP = Q[0], dD2 = Q[1], dD3 = Q[2];
    const double dG1 = Q[3], dG2 = Q[4], dG3 = Q[5];
    const double FA = dG1 / Bn;
    const double FS3 = (dG3 - dSP / n) / Bn;
    const double FS4 = 0.5 * (dG2 + dD2) / Bn;
    const double FS6 = dD2 / Bn;
    const double FS8 = dD3 / Bn;
    const double o = FA * FA + FS3 * FS3 + FS4 * FS4 + FS6 * FS6 + FS8 * FS8;
    out[0] = (float)o;
  }
}

extern "C" void kernel_launch(void* const* d_in, const int* in_sizes, int n_in,
                              void* d_out, int out_size, void* d_ws, size_t ws_size,
                              hipStream_t stream) {
  const float* real = (const float*)d_in[0];
  const float* gen = (const float*)d_in[1];
  double* P = (double*)d_ws;   // NQ * 2 * BLK_PER_WHICH * 8 = 192 KB
  float* out = (float*)d_out;

  dim3 grid(BLK_PER_WHICH, 2);
  sig_flat<<<grid, 256, 0, stream>>>(real, gen, P);
  sig_final<<<1, 256, 0, stream>>>(P, out);
}

// Round 3
// 146.243 us; speedup vs baseline: 1.0089x; 1.0078x over previous
//
#include <hip/hip_runtime.h>

// SigMMDLoss, algebraically flattened (see round-1/2 derivation):
//   A  = p[4095]-p[0]; S3 = p[4095] - SP_row/n; S4 = (A^2+S6)/2;
//   S6 = sum d^2; S8 = sum d^3;  time-only features cancel.
// Global sums needed per array: SP (sum p excl last col), D2, D3,
// G1 = sum_rows A, G2 = sum_rows A^2, G3 = sum_rows p[4095].
// out = sum_q ((F_q^real - F_q^gen)/B)^2.
//
// Round-3 structure: one wave processes TWO full rows (32 KB), 16 float4
// loads batched in flight per row, one reduce tail per wave. 1024 blocks.

constexpr int T_LEN = 4096;
constexpr int B_ROWS = 4096;
constexpr int NQ = 6;                   // sp, d2, d3, g1, g2, g3
constexpr int ROWS_PER_WAVE = 2;
constexpr int BLK = 512;                // blocks per `which`
constexpr int PSTR = 2 * BLK;           // 1024

__global__ __launch_bounds__(256) void sig_flat2(const float* __restrict__ real,
                                                 const float* __restrict__ gen,
                                                 double* __restrict__ P) {
  const int tid = threadIdx.x;
  const int lane = tid & 63;
  const int wid = tid >> 6;
  const int which = blockIdx.y;
  const int wb = blockIdx.x * 4 + wid;          // wave id in [0, 2048)
  const int row0 = wb * ROWS_PER_WAVE;
  const float* base = (which ? gen : real);

  float sp = 0.f, s2 = 0.f, s3 = 0.f;
  double g1 = 0., g2 = 0., g3 = 0.;

#pragma unroll
  for (int rr = 0; rr < ROWS_PER_WAVE; ++rr) {
    const float4* q4 =
        reinterpret_cast<const float4*>(base + (size_t)(row0 + rr) * T_LEN);
    float4 a[16];
    // Batch all 16 row loads (wave reads contiguous 1 KB per instr).
#pragma unroll
    for (int j = 0; j < 16; ++j) a[j] = q4[j * 64 + lane];

    float carry = __shfl(a[0].x, 0, 64);        // p[0]
    const float first = carry;
#pragma unroll
    for (int j = 0; j < 16; ++j) {
      const float pw = __shfl_up(a[j].w, 1, 64);
      const float px = (lane == 0) ? carry : pw;
      const float d0 = a[j].x - px;
      const float d1 = a[j].y - a[j].x;
      const float d2 = a[j].z - a[j].y;
      const float d3 = a[j].w - a[j].z;
      const float e0 = d0 * d0, e1 = d1 * d1, e2 = d2 * d2, e3 = d3 * d3;
      s2 += (e0 + e1) + (e2 + e3);
      s3 += (e0 * d0 + e1 * d1) + (e2 * d2 + e3 * d3);
      sp += (a[j].x + a[j].y) + (a[j].z + a[j].w);
      carry = __shfl(a[j].w, 63, 64);           // p[(j+1)*256 - 1]
    }
    // carry == p[4095] now.
    if (lane == 0) {
      sp -= carry;                              // SP excludes last column
      const double A = (double)carry - (double)first;  // exact telescoped A
      g1 += A;
      g2 += A * A;
      g3 += (double)carry;
    }
  }

  // One wave reduce per wave (fp32 for streams; g* live on lane 0 only).
#pragma unroll
  for (int off = 32; off; off >>= 1) {
    sp += __shfl_down(sp, off, 64);
    s2 += __shfl_down(s2, off, 64);
    s3 += __shfl_down(s3, off, 64);
  }

  __shared__ double sred[4][NQ];
  if (lane == 0) {
    sred[wid][0] = (double)sp;
    sred[wid][1] = (double)s2;
    sred[wid][2] = (double)s3;
    sred[wid][3] = g1;
    sred[wid][4] = g2;
    sred[wid][5] = g3;
  }
  __syncthreads();
  if (tid < NQ) {
    const double s = sred[0][tid] + sred[1][tid] + sred[2][tid] + sred[3][tid];
    P[tid * PSTR + which * BLK + blockIdx.x] = s;
  }
}

__global__ __launch_bounds__(256) void sig_final(const double* __restrict__ P,
                                                 float* __restrict__ out) {
  const int tid = threadIdx.x;
  double loc[NQ] = {0, 0, 0, 0, 0, 0};
  for (int i = tid; i < BLK; i += 256) {
#pragma unroll
    for (int q = 0; q < NQ; ++q)
      loc[q] += P[q * PSTR + i] - P[q * PSTR + BLK + i];
  }
#pragma unroll
  for (int q = 0; q < NQ; ++q)
#pragma unroll
    for (int off = 32; off; off >>= 1) loc[q] += __shfl_down(loc[q], off, 64);

  __shared__ double sred[4][NQ];
  const int lane = tid & 63, wid = tid >> 6;
  if (lane == 0)
    for (int q = 0; q < NQ; ++q) sred[wid][q] = loc[q];
  __syncthreads();
  if (tid == 0) {
    double Q[NQ];
    for (int q = 0; q < NQ; ++q)
      Q[q] = sred[0][q] + sred[1][q] + sred[2][q] + sred[3][q];
    const double n = (double)(T_LEN - 1), Bn = (double)B_ROWS;
    const double FA = Q[3] / Bn;
    const double FS3 = (Q[5] - Q[0] / n) / Bn;
    const double FS4 = 0.5 * (Q[4] + Q[1]) / Bn;
    const double FS6 = Q[1] / Bn;
    const double FS8 = Q[2] / Bn;
    const double o = FA * FA + FS3 * FS3 + FS4 * FS4 + FS6 * FS6 + FS8 * FS8;
    out[0] = (float)o;
  }
}

extern "C" void kernel_launch(void* const* d_in, const int* in_sizes, int n_in,
                              void* d_out, int out_size, void* d_ws, size_t ws_size,
                              hipStream_t stream) {
  const float* real = (const float*)d_in[0];
  const float* gen = (const float*)d_in[1];
  double* P = (double*)d_ws;   // NQ * PSTR * 8 = 48 KB
  float* out = (float*)d_out;

  dim3 grid(BLK, 2);
  sig_flat2<<<grid, 256, 0, stream>>>(real, gen, P);
  sig_final<<<1, 256, 0, stream>>>(P, out);
}